// Round 7
// baseline (2563.747 us; speedup 1.0000x reference)
//
#include <hip/hip_runtime.h>
#include <math.h>

#define DEV static __device__ __forceinline__

DEV void load8(const float* p, float* v) {
    float4 a = *(const float4*)p;
    float4 b = *(const float4*)(p + 4);
    v[0] = a.x; v[1] = a.y; v[2] = a.z; v[3] = a.w;
    v[4] = b.x; v[5] = b.y; v[6] = b.z; v[7] = b.w;
}

// ---------- f32 GEMM body: C[m,n] = sum_k A[m,k]*W[n,k] + bias[n]; N=K=512 ----------
// Strict ascending-k, single-accumulator f32 FMA (reference-matching bit pattern).
DEV void gemm_body(const float* __restrict__ A, const float* __restrict__ W,
                   const float* __restrict__ bias, float* __restrict__ C,
                   int bm, int bn, int tid,
                   float (*As)[68], float (*Bs)[68])
{
    constexpr int BK = 32, NK = 512;
    const int tx = tid & 15, ty = tid >> 4;
    const int lr = tid >> 2, lk = (tid & 3) * 8;
    float acc[4][4] = {};

    for (int k0 = 0; k0 < NK; k0 += BK) {
        float va[8], vb[8];
        load8(A + (size_t)(bm + lr) * NK + k0 + lk, va);
        load8(W + (size_t)(bn + lr) * NK + k0 + lk, vb);
#pragma unroll
        for (int i = 0; i < 8; ++i) { As[lk + i][lr] = va[i]; Bs[lk + i][lr] = vb[i]; }
        __syncthreads();
#pragma unroll
        for (int kk = 0; kk < BK; ++kk) {
            float4 a4 = *(const float4*)&As[kk][ty * 4];
            float4 b4 = *(const float4*)&Bs[kk][tx * 4];
            float a[4] = {a4.x, a4.y, a4.z, a4.w};
            float b[4] = {b4.x, b4.y, b4.z, b4.w};
#pragma unroll
            for (int i = 0; i < 4; ++i)
#pragma unroll
                for (int j = 0; j < 4; ++j)
                    acc[i][j] = fmaf(a[i], b[j], acc[i][j]);
        }
        __syncthreads();
    }

    float4 bvv4 = *(const float4*)&bias[bn + tx * 4];
    float bvv[4] = {bvv4.x, bvv4.y, bvv4.z, bvv4.w};
#pragma unroll
    for (int i = 0; i < 4; ++i) {
        size_t row = (size_t)(bm + ty * 4 + i) * NK + bn + tx * 4;
        float4 o;
        o.x = acc[i][0] + bvv[0];
        o.y = acc[i][1] + bvv[1];
        o.z = acc[i][2] + bvv[2];
        o.w = acc[i][3] + bvv[3];
        *(float4*)&C[row] = o;
    }
}

__global__ __launch_bounds__(256) void gemm_nt512(
    const float* __restrict__ A, const float* __restrict__ W,
    const float* __restrict__ bias, float* __restrict__ C)
{
    __shared__ float As[32][68];
    __shared__ float Bs[32][68];
    gemm_body(A, W, bias, C, blockIdx.y * 64, blockIdx.x * 64, threadIdx.x, As, Bs);
}

// merged Q/K/V projection: grid.y = 128 (Q) + 512 (K) + 512 (V)
__global__ __launch_bounds__(256) void gemm_qkv(
    const float* __restrict__ Aq, const float* __restrict__ Ak, const float* __restrict__ Av,
    const float* __restrict__ Wq, const float* __restrict__ Wk, const float* __restrict__ Wv,
    const float* __restrict__ bq, const float* __restrict__ bk, const float* __restrict__ bv,
    float* __restrict__ Cq, float* __restrict__ Ck, float* __restrict__ Cv)
{
    __shared__ float As[32][68];
    __shared__ float Bs[32][68];
    int yb = blockIdx.y;
    const float *A, *W, *bias; float* C; int bm;
    if (yb < 128)      { A = Aq; W = Wq; bias = bq; C = Cq; bm = yb * 64; }
    else if (yb < 640) { A = Ak; W = Wk; bias = bk; C = Ck; bm = (yb - 128) * 64; }
    else               { A = Av; W = Wv; bias = bv; C = Cv; bm = (yb - 640) * 64; }
    gemm_body(A, W, bias, C, bm, blockIdx.x * 64, threadIdx.x, As, Bs);
}

// exact top-24 insert with (value desc, index asc) ordering; arrays stay in registers
// (all indexing compile-time-unrolled, runtime compares only).
template <int T>
DEV void top24_insert(float v, int idx, float* bv, int* bi,
                      float& curmin, int& minpos, int& minidx)
{
    bool take = (v > curmin) || (v == curmin && idx < minidx);
    if (take) {
#pragma unroll
        for (int t = 0; t < T; ++t)
            if (t == minpos) { bv[t] = v; bi[t] = idx; }
        float mv = bv[0]; int mp = 0, mi = bi[0];
#pragma unroll
        for (int t = 1; t < T; ++t)
            if (bv[t] < mv || (bv[t] == mv && bi[t] > mi)) { mv = bv[t]; mp = t; mi = bi[t]; }
        curmin = mv; minpos = mp; minidx = mi;
    }
}

// ---------- fused: f32 screen -> register tau-filter -> (val,idx) pool append -> drain top-24 -> top-32 -> PV ----------
// Screen: 32q x 128m tiles; thread (qy=tid>>5, tx=tid&31) computes rows qy+8i, cols tx+32jj (4q x 4m),
// strict ascending-d single-accumulator f32 FMA * 0.125f (bit-identical to the round-2 pass).
// Filter: per-thread top-2 per row-slot; tau[row] = half-wave(32) shfl-min of 2nd-bests => 64 distinct
// witnesses >= tau, so skipping v < tau is exact (strictly-greater value, index irrelevant).
// tau is monotone, so every candidate with final v >= tau was appended when seen.
// Appends write (v, idx) float2 -- the exact screen score, NO rescore needed.
// Drain: after appends, if a row's count > CAP-128, its 8 merge lanes fold the pool into per-lane
// exact top-24 (stride-8 position share) and reset; per-tile appends per row <= 128 => no overflow.
// Final: unchanged 8-lane exact top-32 extraction (value desc, index asc) + softmax + PV.
// Workspace: 160 MB arrays + 80 MB pool = 240 MB (within the proven-safe envelope).
__global__ __launch_bounds__(256) void topk_attn_fused(
    const float* __restrict__ Qf, const float* __restrict__ Kf,
    const float* __restrict__ Vp, float* __restrict__ Xp,
    float2* __restrict__ gpool)
{
    constexpr int LQ = 1024, LM = 4096, DK = 64, D = 512, QT = 32, MT = 128, TK = 32, T = 24;
    constexpr int CAP = 160, THR = CAP - 128;   // drain threshold (invariant: cnt<=THR at tile start)
    // LDS: ks f32[128][68] = 34816 B; qs f32[32][68] = 8704 B; cnt int[32].
    //   wsel f32[32][33] + isel i32[32][33] (8448 B) alias ks (post-loop only).
    __shared__ __align__(16) char smem[34816 + 8704 + 128];
    float (*ks)[68]   = (float (*)[68])(smem);
    float (*wsel)[33] = (float (*)[33])(smem);
    int   (*isel)[33] = (int   (*)[33])(smem + 4224);
    float (*qs)[68]   = (float (*)[68])(smem + 34816);
    int*  cnt         = (int*)(smem + 34816 + 8704);

    const int tid  = threadIdx.x;
    const int lane = tid & 63;
    const int w    = tid >> 6;
    const int g    = lane >> 3, j = lane & 7;
    const int r    = 8 * w + g;                    // merge row owned by this lane (drain/final role)
    const int qt = blockIdx.x, h = blockIdx.y, b = blockIdx.z;

    // per-block pool base; per-row segment [row*CAP, row*CAP+CAP)
    const size_t bb = (size_t)(((b * 8 + h) * 32 + qt) * 32) * CAP;

    // stage 32x64 Q tile (f32)
    {
        int rr = tid >> 3, d0 = (tid & 7) * 8;
        const float* src = Qf + ((size_t)(b * LQ + qt * QT + rr) * D + h * DK + d0);
        float4 a = *(const float4*)src;
        float4 c = *(const float4*)(src + 4);
        *(float4*)&qs[rr][d0]     = a;
        *(float4*)&qs[rr][d0 + 4] = c;
    }
    if (tid < 32) cnt[tid] = 0;

    // per-lane exact top-24 of my pool share (accumulated across drains)
    float bv[T]; int bi[T];
#pragma unroll
    for (int t = 0; t < T; ++t) { bv[t] = -INFINITY; bi[t] = 0; }
    float curmin = -INFINITY; int minpos = 0, minidx = 0;

    // per-thread filter state: top-2 per row-slot (rows qy+8i), and tau
    float s0[4], s1[4], tau[4];
#pragma unroll
    for (int i = 0; i < 4; ++i) { s0[i] = -INFINITY; s1[i] = -INFINITY; tau[i] = -INFINITY; }

    const int qy = tid >> 5, tx = tid & 31;
    const int srr = tid >> 2, sd0 = (tid & 3) * 16;
    __syncthreads();

#pragma unroll 1
    for (int mc = 0; mc < LM; mc += MT) {
        // stage 128x64 K tile (two 64-row passes, coalesced)
#pragma unroll
        for (int p = 0; p < 2; ++p) {
            const float* src = Kf + ((size_t)(b * LM + mc + 64 * p + srr) * D + h * DK + sd0);
#pragma unroll
            for (int i2 = 0; i2 < 16; i2 += 4)
                *(float4*)&ks[64 * p + srr][sd0 + i2] = *(const float4*)(src + i2);
        }
        __syncthreads();

        // 4q x 4m per thread, strict ascending-d single-accumulator f32 FMA
        float acc[4][4] = {};
#pragma unroll 2
        for (int dc = 0; dc < DK; dc += 4) {
            float4 qa[4], kb[4];
#pragma unroll
            for (int i = 0; i < 4; ++i) qa[i] = *(const float4*)&qs[qy + 8 * i][dc];
#pragma unroll
            for (int jj = 0; jj < 4; ++jj) kb[jj] = *(const float4*)&ks[tx + 32 * jj][dc];
#pragma unroll
            for (int i = 0; i < 4; ++i)
#pragma unroll
                for (int jj = 0; jj < 4; ++jj) {
                    acc[i][jj] = fmaf(qa[i].x, kb[jj].x, acc[i][jj]);
                    acc[i][jj] = fmaf(qa[i].y, kb[jj].y, acc[i][jj]);
                    acc[i][jj] = fmaf(qa[i].z, kb[jj].z, acc[i][jj]);
                    acc[i][jj] = fmaf(qa[i].w, kb[jj].w, acc[i][jj]);
                }
        }

        // scale in place (bit-identical final scores), update per-row top-2
#pragma unroll
        for (int i = 0; i < 4; ++i)
#pragma unroll
            for (int jj = 0; jj < 4; ++jj) {
                float v = acc[i][jj] * 0.125f;
                acc[i][jj] = v;
                if (v > s1[i]) {
                    if (v > s0[i]) { s1[i] = s0[i]; s0[i] = v; }
                    else           { s1[i] = v; }
                }
            }

        // tau[i] = min over the 32 threads of this qy-group of their 2nd-best (half-wave shfl)
#pragma unroll
        for (int i = 0; i < 4; ++i) {
            float t4 = s1[i];
            t4 = fminf(t4, __shfl_xor(t4, 1));
            t4 = fminf(t4, __shfl_xor(t4, 2));
            t4 = fminf(t4, __shfl_xor(t4, 4));
            t4 = fminf(t4, __shfl_xor(t4, 8));
            t4 = fminf(t4, __shfl_xor(t4, 16));
            tau[i] = t4;
        }

        // append all candidates with v >= tau (exact-coverage filter) as (value, index)
#pragma unroll
        for (int i = 0; i < 4; ++i) {
            int row = qy + 8 * i;
#pragma unroll
            for (int jj = 0; jj < 4; ++jj) {
                float v = acc[i][jj];
                if (v >= tau[i]) {
                    int pos = atomicAdd(&cnt[row], 1);
                    if (pos < CAP)   // invariant guarantees this; guard prevents any OOB path
                        gpool[bb + (size_t)row * CAP + pos] =
                            make_float2(v, __int_as_float(mc + tx + 32 * jj));
                }
            }
        }
        __syncthreads();   // appends visible to drain lanes; ks reads done before next staging

        // drain: if my row's pool is near capacity, fold my stride-8 share into top-24
        {
            int nc = min(cnt[r], CAP);
            if (nc > THR) {
#pragma unroll 1
                for (int p = j; p < nc; p += 8) {
                    float2 e = gpool[bb + (size_t)r * CAP + p];
                    top24_insert<T>(e.x, __float_as_int(e.y), bv, bi, curmin, minpos, minidx);
                }
                if (j == 0) cnt[r] = 0;
            }
        }
        // cnt reset ordered before next tile's appends by the next stage barrier
    }

    // final drain of the residual pool
    {
        int nc = min(cnt[r], CAP);
#pragma unroll 1
        for (int p = j; p < nc; p += 8) {
            float2 e = gpool[bb + (size_t)r * CAP + p];
            top24_insert<T>(e.x, __float_as_int(e.y), bv, bi, curmin, minpos, minidx);
        }
    }

    // exact top-32 among the row's pool (f32 order, lower index on ties)
    unsigned cons = 0;
    float m0 = 0.0f;
    double sum_part = 0.0;
#pragma unroll 1
    for (int t32 = 0; t32 < TK; ++t32) {
        float lm = -INFINITY; int li = 0x7fffffff; int lp = -1;
#pragma unroll
        for (int t = 0; t < T; ++t) {
            bool ok = !(cons & (1u << t));
            if (ok && (bv[t] > lm || (bv[t] == lm && bi[t] < li))) {
                lm = bv[t]; li = bi[t]; lp = t;
            }
        }
        float gv = lm; int gi = li;
#pragma unroll
        for (int k = 1; k < 8; k <<= 1) {
            float ov = __shfl_xor(gv, k);
            int   oi = __shfl_xor(gi, k);
            if (ov > gv || (ov == gv && oi < gi)) { gv = ov; gi = oi; }
        }
        if (lp >= 0 && gv == lm && gi == li) cons |= 1u << lp;   // winner's owner consumes
        if (t32 == 0) m0 = gv;
        if ((t32 & 7) == j) {
            double e = exp((double)(gv - m0));
            sum_part += e;
            isel[r][t32] = gi;
            wsel[r][t32] = (float)e;       // unnormalized; rescaled below
        }
    }
#pragma unroll
    for (int k = 1; k < 8; k <<= 1) sum_part += __shfl_xor(sum_part, k);
    {
        double inv = 1.0 / sum_part;
#pragma unroll
        for (int tt = 0; tt < 4; ++tt) {
            int t = 8 * tt + j;
            wsel[r][t] = (float)((double)wsel[r][t] * inv);
        }
    }
    __syncthreads();

    // PV: gather selected V rows (f32), write X[b, q, h*64+d]
    {
        int rr = tid >> 3, d0 = (tid & 7) * 8;
        float4 a0 = {0, 0, 0, 0}, a1 = {0, 0, 0, 0};
#pragma unroll 1
        for (int t = 0; t < TK; ++t) {
            float ww = wsel[rr][t];
            int mi   = isel[rr][t];
            const float* vp = Vp + ((size_t)(b * LM + mi) * D + h * DK + d0);
            float4 v0 = *(const float4*)vp;
            float4 v1 = *(const float4*)(vp + 4);
            a0.x = fmaf(ww, v0.x, a0.x); a0.y = fmaf(ww, v0.y, a0.y);
            a0.z = fmaf(ww, v0.z, a0.z); a0.w = fmaf(ww, v0.w, a0.w);
            a1.x = fmaf(ww, v1.x, a1.x); a1.y = fmaf(ww, v1.y, a1.y);
            a1.z = fmaf(ww, v1.z, a1.z); a1.w = fmaf(ww, v1.w, a1.w);
        }
        float* xp = Xp + ((size_t)(b * LQ + qt * QT + rr) * D + h * DK + d0);
        *(float4*)xp       = a0;
        *(float4*)(xp + 4) = a1;
    }
}

extern "C" void kernel_launch(void* const* d_in, const int* in_sizes, int n_in,
                              void* d_out, int out_size, void* d_ws, size_t ws_size,
                              hipStream_t stream) {
    const float* query = (const float*)d_in[0];
    const float* key   = (const float*)d_in[1];
    const float* value = (const float*)d_in[2];
    const float* Wq    = (const float*)d_in[3];
    const float* bq    = (const float*)d_in[4];
    const float* Wk    = (const float*)d_in[5];
    const float* bk    = (const float*)d_in[6];
    const float* Wv    = (const float*)d_in[7];
    const float* bv    = (const float*)d_in[8];
    const float* Wo    = (const float*)d_in[9];
    const float* bo    = (const float*)d_in[10];
    float* out = (float*)d_out;

    // ws: V f32 [32768,512] | X f32 [8192,512] | Q f32 [8192,512] | K f32 [32768,512] (160 MB)
    //     | gpool float2 [2048*32*160] (80 MB)  -- total 240 MB
    float* Vp = (float*)d_ws;
    float* Xp = Vp + (size_t)32768 * 512;
    float* Qf = Xp + (size_t)8192 * 512;
    float* Kf = Qf + (size_t)8192 * 512;
    float2* gpool = (float2*)((char*)d_ws + (size_t)167772160);

    dim3 blk(256);
    gemm_qkv<<<dim3(8, 1152), blk, 0, stream>>>(query, key, value,
                                                Wq, Wk, Wv, bq, bk, bv,
                                                Qf, Kf, Vp);
    topk_attn_fused<<<dim3(32, 8, 8), blk, 0, stream>>>(Qf, Kf, Vp, Xp, gpool);
    gemm_nt512<<<dim3(8, 128), blk, 0, stream>>>(Xp, Wo, bo, out);
}

// Round 8
// 2456.899 us; speedup vs baseline: 1.0435x; 1.0435x over previous
//
#include <hip/hip_runtime.h>
#include <math.h>

#define DEV static __device__ __forceinline__

DEV void load8(const float* p, float* v) {
    float4 a = *(const float4*)p;
    float4 b = *(const float4*)(p + 4);
    v[0] = a.x; v[1] = a.y; v[2] = a.z; v[3] = a.w;
    v[4] = b.x; v[5] = b.y; v[6] = b.z; v[7] = b.w;
}

// ---------- f32 GEMM body: C[m,n] = sum_k A[m,k]*W[n,k] + bias[n]; N=K=512 ----------
// Strict ascending-k, single-accumulator f32 FMA (reference-matching bit pattern).
DEV void gemm_body(const float* __restrict__ A, const float* __restrict__ W,
                   const float* __restrict__ bias, float* __restrict__ C,
                   int bm, int bn, int tid,
                   float (*As)[68], float (*Bs)[68])
{
    constexpr int BK = 32, NK = 512;
    const int tx = tid & 15, ty = tid >> 4;
    const int lr = tid >> 2, lk = (tid & 3) * 8;
    float acc[4][4] = {};

    for (int k0 = 0; k0 < NK; k0 += BK) {
        float va[8], vb[8];
        load8(A + (size_t)(bm + lr) * NK + k0 + lk, va);
        load8(W + (size_t)(bn + lr) * NK + k0 + lk, vb);
#pragma unroll
        for (int i = 0; i < 8; ++i) { As[lk + i][lr] = va[i]; Bs[lk + i][lr] = vb[i]; }
        __syncthreads();
#pragma unroll
        for (int kk = 0; kk < BK; ++kk) {
            float4 a4 = *(const float4*)&As[kk][ty * 4];
            float4 b4 = *(const float4*)&Bs[kk][tx * 4];
            float a[4] = {a4.x, a4.y, a4.z, a4.w};
            float b[4] = {b4.x, b4.y, b4.z, b4.w};
#pragma unroll
            for (int i = 0; i < 4; ++i)
#pragma unroll
                for (int j = 0; j < 4; ++j)
                    acc[i][j] = fmaf(a[i], b[j], acc[i][j]);
        }
        __syncthreads();
    }

    float4 bvv4 = *(const float4*)&bias[bn + tx * 4];
    float bvv[4] = {bvv4.x, bvv4.y, bvv4.z, bvv4.w};
#pragma unroll
    for (int i = 0; i < 4; ++i) {
        size_t row = (size_t)(bm + ty * 4 + i) * NK + bn + tx * 4;
        float4 o;
        o.x = acc[i][0] + bvv[0];
        o.y = acc[i][1] + bvv[1];
        o.z = acc[i][2] + bvv[2];
        o.w = acc[i][3] + bvv[3];
        *(float4*)&C[row] = o;
    }
}

__global__ __launch_bounds__(256) void gemm_nt512(
    const float* __restrict__ A, const float* __restrict__ W,
    const float* __restrict__ bias, float* __restrict__ C)
{
    __shared__ float As[32][68];
    __shared__ float Bs[32][68];
    gemm_body(A, W, bias, C, blockIdx.y * 64, blockIdx.x * 64, threadIdx.x, As, Bs);
}

// merged Q/K/V projection: grid.y = 128 (Q) + 512 (K) + 512 (V)
__global__ __launch_bounds__(256) void gemm_qkv(
    const float* __restrict__ Aq, const float* __restrict__ Ak, const float* __restrict__ Av,
    const float* __restrict__ Wq, const float* __restrict__ Wk, const float* __restrict__ Wv,
    const float* __restrict__ bq, const float* __restrict__ bk, const float* __restrict__ bv,
    float* __restrict__ Cq, float* __restrict__ Ck, float* __restrict__ Cv)
{
    __shared__ float As[32][68];
    __shared__ float Bs[32][68];
    int yb = blockIdx.y;
    const float *A, *W, *bias; float* C; int bm;
    if (yb < 128)      { A = Aq; W = Wq; bias = bq; C = Cq; bm = yb * 64; }
    else if (yb < 640) { A = Ak; W = Wk; bias = bk; C = Ck; bm = (yb - 128) * 64; }
    else               { A = Av; W = Wv; bias = bv; C = Cv; bm = (yb - 640) * 64; }
    gemm_body(A, W, bias, C, bm, blockIdx.x * 64, threadIdx.x, As, Bs);
}

// ---------- fused: f32 screen (4q x 8m regs) -> per-lane reg top-24 -> top-32 -> PV ----------
// Screen: 32q x 256m tiles; thread (qy=tid>>5, tx=tid&31) computes rows qy+8i, cols tx+32jj,
// strict ascending-d single-accumulator f32 FMA * 0.125f (bit-identical to the round-2 pass).
// ks is chunk-XOR swizzled (phys 16B-chunk = c ^ ((row>>3)&3)) so the 4 lanes sharing a bank
// phase (tx, tx+8, tx+16, tx+24) hit 4 distinct bank groups -> conflict-free b128 reads.
// Merge (round-2 proven): lane (w,g,j) owns row r=8w+g, cols == j (mod 8), ascending order,
// per-lane reg top-24 with strict > (earliest index kept on ties). Union of 8 lanes' top-24
// covers the row's top-32. Final extraction (value desc, index asc) + softmax + PV unchanged.
__global__ __launch_bounds__(256) void topk_attn_fused(
    const float* __restrict__ Qf, const float* __restrict__ Kf,
    const float* __restrict__ Vp, float* __restrict__ Xp)
{
    constexpr int LQ = 1024, LM = 4096, DK = 64, D = 512, QT = 32, MT = 256, TK = 32, T = 24;
    // LDS: ks f32[256][68] = 69632 B.
    //   sc f32[32][264] (33792 B) aliases ks rows 128..255 (offset 34816) -- barrier-separated.
    //   wsel f32[32][33] + isel i32[32][33] (8448 B) alias ks rows 0.. (post-loop only).
    //   qs f32[32][68] (8704 B) separate.
    __shared__ __align__(16) char smem[69632 + 8704];
    float (*ks)[68]   = (float (*)[68])(smem);
    float (*sc)[264]  = (float (*)[264])(smem + 34816);
    float (*wsel)[33] = (float (*)[33])(smem);
    int   (*isel)[33] = (int   (*)[33])(smem + 4224);
    float (*qs)[68]   = (float (*)[68])(smem + 69632);

    const int tid  = threadIdx.x;
    const int lane = tid & 63;
    const int w    = tid >> 6;
    const int g    = lane >> 3, j = lane & 7;
    const int r    = 8 * w + g;                    // merge row owned by this lane
    const int qt = blockIdx.x, h = blockIdx.y, b = blockIdx.z;

    // stage 32x64 Q tile (f32)
    {
        int rr = tid >> 3, d0 = (tid & 7) * 8;
        const float* src = Qf + ((size_t)(b * LQ + qt * QT + rr) * D + h * DK + d0);
        float4 a = *(const float4*)src;
        float4 c = *(const float4*)(src + 4);
        *(float4*)&qs[rr][d0]     = a;
        *(float4*)&qs[rr][d0 + 4] = c;
    }

    // per-lane top-T registers (fully unrolled access only)
    float bv[T]; int bi[T];
#pragma unroll
    for (int t = 0; t < T; ++t) { bv[t] = -INFINITY; bi[t] = 0; }
    float curmin = -INFINITY; int minpos = 0;

    const int qy = tid >> 5, tx = tid & 31;
    const int srr = tid >> 2, sd0 = (tid & 3) * 16;
    const int dxw = (srr >> 3) & 3;    // staging swizzle key
    const int dxr = (tx >> 3) & 3;     // read swizzle key (same for all jj of a lane)
    __syncthreads();

#pragma unroll 1
    for (int mc = 0; mc < LM; mc += MT) {
        // stage 256x64 K tile (four 64-row passes), chunk-XOR swizzled
#pragma unroll
        for (int p = 0; p < 4; ++p) {
            const float* src = Kf + ((size_t)(b * LM + mc + 64 * p + srr) * D + h * DK + sd0);
            int row = 64 * p + srr;
#pragma unroll
            for (int i2 = 0; i2 < 16; i2 += 4) {
                int c = (sd0 + i2) >> 2;
                *(float4*)&ks[row][(c ^ dxw) << 2] = *(const float4*)(src + i2);
            }
        }
        __syncthreads();

        // 4q x 8m per thread, strict ascending-d single-accumulator f32 FMA
        float acc[4][8] = {};
#pragma unroll 2
        for (int dc = 0; dc < DK; dc += 4) {
            int col = (((dc >> 2) ^ dxr) << 2);
            float4 qa[4], kb[8];
#pragma unroll
            for (int i = 0; i < 4; ++i) qa[i] = *(const float4*)&qs[qy + 8 * i][dc];
#pragma unroll
            for (int jj = 0; jj < 8; ++jj) kb[jj] = *(const float4*)&ks[tx + 32 * jj][col];
#pragma unroll
            for (int i = 0; i < 4; ++i)
#pragma unroll
                for (int jj = 0; jj < 8; ++jj) {
                    acc[i][jj] = fmaf(qa[i].x, kb[jj].x, acc[i][jj]);
                    acc[i][jj] = fmaf(qa[i].y, kb[jj].y, acc[i][jj]);
                    acc[i][jj] = fmaf(qa[i].z, kb[jj].z, acc[i][jj]);
                    acc[i][jj] = fmaf(qa[i].w, kb[jj].w, acc[i][jj]);
                }
        }
        __syncthreads();   // all ks reads done before sc (aliased) is written

#pragma unroll
        for (int i = 0; i < 4; ++i)
#pragma unroll
            for (int jj = 0; jj < 8; ++jj)
                sc[qy + 8 * i][tx + 32 * jj] = acc[i][jj] * 0.125f;
        __syncthreads();

        // per-lane merge: 32 candidates of my row (cols 8c+j), strict > keeps earliest index
#pragma unroll
        for (int c = 0; c < 32; ++c) {
            float v = sc[r][8 * c + j];
            if (v > curmin) {
                int idx = mc + 8 * c + j;
#pragma unroll
                for (int t = 0; t < T; ++t)
                    if (t == minpos) { bv[t] = v; bi[t] = idx; }
                float mv = bv[0]; int mp = 0;
#pragma unroll
                for (int t = 1; t < T; ++t)
                    if (bv[t] < mv) { mv = bv[t]; mp = t; }
                curmin = mv; minpos = mp;
            }
        }
        __syncthreads();   // merge reads done before next staging overwrites ks/sc
    }

    // exact top-32 among the group's 192 candidates on the f32 screen scores
    // (f32 order, lower index on ties — jax.lax.top_k semantics)
    unsigned cons = 0;
    float m0 = 0.0f;
    double sum_part = 0.0;
#pragma unroll 1
    for (int t32 = 0; t32 < TK; ++t32) {
        float lm = -INFINITY; int li = 0x7fffffff; int lp = -1;
#pragma unroll
        for (int t = 0; t < T; ++t) {
            bool ok = !(cons & (1u << t));
            if (ok && (bv[t] > lm || (bv[t] == lm && bi[t] < li))) {
                lm = bv[t]; li = bi[t]; lp = t;
            }
        }
        float gv = lm; int gi = li;
#pragma unroll
        for (int k = 1; k < 8; k <<= 1) {
            float ov = __shfl_xor(gv, k);
            int   oi = __shfl_xor(gi, k);
            if (ov > gv || (ov == gv && oi < gi)) { gv = ov; gi = oi; }
        }
        if (lp >= 0 && gv == lm && gi == li) cons |= 1u << lp;   // winner's owner consumes
        if (t32 == 0) m0 = gv;
        if ((t32 & 7) == j) {
            double e = exp((double)(gv - m0));
            sum_part += e;
            isel[r][t32] = gi;
            wsel[r][t32] = (float)e;       // unnormalized; rescaled below
        }
    }
#pragma unroll
    for (int k = 1; k < 8; k <<= 1) sum_part += __shfl_xor(sum_part, k);
    {
        double inv = 1.0 / sum_part;
#pragma unroll
        for (int tt = 0; tt < 4; ++tt) {
            int t = 8 * tt + j;
            wsel[r][t] = (float)((double)wsel[r][t] * inv);
        }
    }
    __syncthreads();

    // PV: gather selected V rows (f32), write X[b, q, h*64+d]
    {
        int rr = tid >> 3, d0 = (tid & 7) * 8;
        float4 a0 = {0, 0, 0, 0}, a1 = {0, 0, 0, 0};
#pragma unroll 1
        for (int t = 0; t < TK; ++t) {
            float ww = wsel[rr][t];
            int mi   = isel[rr][t];
            const float* vp = Vp + ((size_t)(b * LM + mi) * D + h * DK + d0);
            float4 v0 = *(const float4*)vp;
            float4 v1 = *(const float4*)(vp + 4);
            a0.x = fmaf(ww, v0.x, a0.x); a0.y = fmaf(ww, v0.y, a0.y);
            a0.z = fmaf(ww, v0.z, a0.z); a0.w = fmaf(ww, v0.w, a0.w);
            a1.x = fmaf(ww, v1.x, a1.x); a1.y = fmaf(ww, v1.y, a1.y);
            a1.z = fmaf(ww, v1.z, a1.z); a1.w = fmaf(ww, v1.w, a1.w);
        }
        float* xp = Xp + ((size_t)(b * LQ + qt * QT + rr) * D + h * DK + d0);
        *(float4*)xp       = a0;
        *(float4*)(xp + 4) = a1;
    }
}

extern "C" void kernel_launch(void* const* d_in, const int* in_sizes, int n_in,
                              void* d_out, int out_size, void* d_ws, size_t ws_size,
                              hipStream_t stream) {
    const float* query = (const float*)d_in[0];
    const float* key   = (const float*)d_in[1];
    const float* value = (const float*)d_in[2];
    const float* Wq    = (const float*)d_in[3];
    const float* bq    = (const float*)d_in[4];
    const float* Wk    = (const float*)d_in[5];
    const float* bk    = (const float*)d_in[6];
    const float* Wv    = (const float*)d_in[7];
    const float* bv    = (const float*)d_in[8];
    const float* Wo    = (const float*)d_in[9];
    const float* bo    = (const float*)d_in[10];
    float* out = (float*)d_out;

    // ws: V f32 [32768,512] | X f32 [8192,512] | Q f32 [8192,512] | K f32 [32768,512]  (160 MB)
    float* Vp = (float*)d_ws;
    float* Xp = Vp + (size_t)32768 * 512;
    float* Qf = Xp + (size_t)8192 * 512;
    float* Kf = Qf + (size_t)8192 * 512;

    dim3 blk(256);
    gemm_qkv<<<dim3(8, 1152), blk, 0, stream>>>(query, key, value,
                                                Wq, Wk, Wv, bq, bk, bv,
                                                Qf, Kf, Vp);
    topk_attn_fused<<<dim3(32, 8, 8), blk, 0, stream>>>(Qf, Kf, Vp, Xp);
    gemm_nt512<<<dim3(8, 128), blk, 0, stream>>>(Xp, Wo, bo, out);
}

// Round 9
// 2231.936 us; speedup vs baseline: 1.1487x; 1.1008x over previous
//
#include <hip/hip_runtime.h>
#include <math.h>

#define DEV static __device__ __forceinline__

DEV void load8(const float* p, float* v) {
    float4 a = *(const float4*)p;
    float4 b = *(const float4*)(p + 4);
    v[0] = a.x; v[1] = a.y; v[2] = a.z; v[3] = a.w;
    v[4] = b.x; v[5] = b.y; v[6] = b.z; v[7] = b.w;
}

// ---------- f32 GEMM body: C[m,n] = sum_k A[m,k]*W[n,k] + bias[n]; N=K=512 ----------
// Strict ascending-k, single-accumulator f32 FMA (reference-matching bit pattern).
DEV void gemm_body(const float* __restrict__ A, const float* __restrict__ W,
                   const float* __restrict__ bias, float* __restrict__ C,
                   int bm, int bn, int tid,
                   float (*As)[68], float (*Bs)[68])
{
    constexpr int BK = 32, NK = 512;
    const int tx = tid & 15, ty = tid >> 4;
    const int lr = tid >> 2, lk = (tid & 3) * 8;
    float acc[4][4] = {};

    for (int k0 = 0; k0 < NK; k0 += BK) {
        float va[8], vb[8];
        load8(A + (size_t)(bm + lr) * NK + k0 + lk, va);
        load8(W + (size_t)(bn + lr) * NK + k0 + lk, vb);
#pragma unroll
        for (int i = 0; i < 8; ++i) { As[lk + i][lr] = va[i]; Bs[lk + i][lr] = vb[i]; }
        __syncthreads();
#pragma unroll
        for (int kk = 0; kk < BK; ++kk) {
            float4 a4 = *(const float4*)&As[kk][ty * 4];
            float4 b4 = *(const float4*)&Bs[kk][tx * 4];
            float a[4] = {a4.x, a4.y, a4.z, a4.w};
            float b[4] = {b4.x, b4.y, b4.z, b4.w};
#pragma unroll
            for (int i = 0; i < 4; ++i)
#pragma unroll
                for (int j = 0; j < 4; ++j)
                    acc[i][j] = fmaf(a[i], b[j], acc[i][j]);
        }
        __syncthreads();
    }

    float4 bvv4 = *(const float4*)&bias[bn + tx * 4];
    float bvv[4] = {bvv4.x, bvv4.y, bvv4.z, bvv4.w};
#pragma unroll
    for (int i = 0; i < 4; ++i) {
        size_t row = (size_t)(bm + ty * 4 + i) * NK + bn + tx * 4;
        float4 o;
        o.x = acc[i][0] + bvv[0];
        o.y = acc[i][1] + bvv[1];
        o.z = acc[i][2] + bvv[2];
        o.w = acc[i][3] + bvv[3];
        *(float4*)&C[row] = o;
    }
}

__global__ __launch_bounds__(256) void gemm_nt512(
    const float* __restrict__ A, const float* __restrict__ W,
    const float* __restrict__ bias, float* __restrict__ C)
{
    __shared__ float As[32][68];
    __shared__ float Bs[32][68];
    gemm_body(A, W, bias, C, blockIdx.y * 64, blockIdx.x * 64, threadIdx.x, As, Bs);
}

// merged Q/K/V projection: grid.y = 128 (Q) + 512 (K) + 512 (V)
__global__ __launch_bounds__(256) void gemm_qkv(
    const float* __restrict__ Aq, const float* __restrict__ Ak, const float* __restrict__ Av,
    const float* __restrict__ Wq, const float* __restrict__ Wk, const float* __restrict__ Wv,
    const float* __restrict__ bq, const float* __restrict__ bk, const float* __restrict__ bv,
    float* __restrict__ Cq, float* __restrict__ Ck, float* __restrict__ Cv)
{
    __shared__ float As[32][68];
    __shared__ float Bs[32][68];
    int yb = blockIdx.y;
    const float *A, *W, *bias; float* C; int bm;
    if (yb < 128)      { A = Aq; W = Wq; bias = bq; C = Cq; bm = yb * 64; }
    else if (yb < 640) { A = Ak; W = Wk; bias = bk; C = Ck; bm = (yb - 128) * 64; }
    else               { A = Av; W = Wv; bias = bv; C = Cv; bm = (yb - 640) * 64; }
    gemm_body(A, W, bias, C, bm, blockIdx.x * 64, threadIdx.x, As, Bs);
}

// ---------- fused: f32 screen (4q x 4m regs, MT=128) -> per-lane reg top-24 -> top-32 -> PV ----------
// Screen: 32q x 128m tiles; thread (qy=tid>>5, tx=tid&31) computes rows qy+8i, cols tx+32jj,
// strict ascending-d single-accumulator f32 FMA * 0.125f (bit-identical to rounds 2/4 passes).
// Merge (rounds 2/4 proven): lane (w,g,j) owns row r=8w+g, cols == j (mod 8), ascending order,
// per-lane reg top-24 with strict > (earliest index kept on ties).
// Final extraction (value desc, index asc) + softmax + PV unchanged from round 2.
// LDS 43.5 KB -> 3 blocks/CU; 4 barriers/tile x 32 tiles.
__global__ __launch_bounds__(256) void topk_attn_fused(
    const float* __restrict__ Qf, const float* __restrict__ Kf,
    const float* __restrict__ Vp, float* __restrict__ Xp)
{
    constexpr int LQ = 1024, LM = 4096, DK = 64, D = 512, QT = 32, MT = 128, TK = 32, T = 24;
    // LDS: ks f32[128][68] = 34816 B.
    //   sc f32[32][136] (17408 B) aliases ks rows 64..127 (offset 17408) -- barrier-separated.
    //   wsel f32[32][33] + isel i32[32][33] (8448 B) alias ks rows 0.. (post-loop only).
    //   qs f32[32][68] (8704 B) separate.
    __shared__ __align__(16) char smem[34816 + 8704];
    float (*ks)[68]   = (float (*)[68])(smem);
    float (*sc)[136]  = (float (*)[136])(smem + 17408);
    float (*wsel)[33] = (float (*)[33])(smem);
    int   (*isel)[33] = (int   (*)[33])(smem + 4224);
    float (*qs)[68]   = (float (*)[68])(smem + 34816);

    const int tid  = threadIdx.x;
    const int lane = tid & 63;
    const int w    = tid >> 6;
    const int g    = lane >> 3, j = lane & 7;
    const int r    = 8 * w + g;                    // merge row owned by this lane
    const int qt = blockIdx.x, h = blockIdx.y, b = blockIdx.z;

    // stage 32x64 Q tile (f32)
    {
        int rr = tid >> 3, d0 = (tid & 7) * 8;
        const float* src = Qf + ((size_t)(b * LQ + qt * QT + rr) * D + h * DK + d0);
        float4 a = *(const float4*)src;
        float4 c = *(const float4*)(src + 4);
        *(float4*)&qs[rr][d0]     = a;
        *(float4*)&qs[rr][d0 + 4] = c;
    }

    // per-lane top-T registers (fully unrolled access only)
    float bv[T]; int bi[T];
#pragma unroll
    for (int t = 0; t < T; ++t) { bv[t] = -INFINITY; bi[t] = 0; }
    float curmin = -INFINITY; int minpos = 0;

    const int qy = tid >> 5, tx = tid & 31;
    const int srr = tid >> 2, sd0 = (tid & 3) * 16;
    __syncthreads();

#pragma unroll 1
    for (int mc = 0; mc < LM; mc += MT) {
        // stage 128x64 K tile (two 64-row passes, coalesced b128 writes)
#pragma unroll
        for (int p = 0; p < 2; ++p) {
            const float* src = Kf + ((size_t)(b * LM + mc + 64 * p + srr) * D + h * DK + sd0);
#pragma unroll
            for (int i2 = 0; i2 < 16; i2 += 4)
                *(float4*)&ks[64 * p + srr][sd0 + i2] = *(const float4*)(src + i2);
        }
        __syncthreads();

        // 4q x 4m per thread, strict ascending-d single-accumulator f32 FMA
        float acc[4][4] = {};
#pragma unroll 2
        for (int dc = 0; dc < DK; dc += 4) {
            float4 qa[4], kb[4];
#pragma unroll
            for (int i = 0; i < 4; ++i) qa[i] = *(const float4*)&qs[qy + 8 * i][dc];
#pragma unroll
            for (int jj = 0; jj < 4; ++jj) kb[jj] = *(const float4*)&ks[tx + 32 * jj][dc];
#pragma unroll
            for (int i = 0; i < 4; ++i)
#pragma unroll
                for (int jj = 0; jj < 4; ++jj) {
                    acc[i][jj] = fmaf(qa[i].x, kb[jj].x, acc[i][jj]);
                    acc[i][jj] = fmaf(qa[i].y, kb[jj].y, acc[i][jj]);
                    acc[i][jj] = fmaf(qa[i].z, kb[jj].z, acc[i][jj]);
                    acc[i][jj] = fmaf(qa[i].w, kb[jj].w, acc[i][jj]);
                }
        }
        __syncthreads();   // all ks reads done before sc (aliased over ks rows 64..127) is written

#pragma unroll
        for (int i = 0; i < 4; ++i)
#pragma unroll
            for (int jj = 0; jj < 4; ++jj)
                sc[qy + 8 * i][tx + 32 * jj] = acc[i][jj] * 0.125f;
        __syncthreads();

        // per-lane merge: 16 candidates of my row (cols 8c+j), strict > keeps earliest index
#pragma unroll
        for (int c = 0; c < 16; ++c) {
            float v = sc[r][8 * c + j];
            if (v > curmin) {
                int idx = mc + 8 * c + j;
#pragma unroll
                for (int t = 0; t < T; ++t)
                    if (t == minpos) { bv[t] = v; bi[t] = idx; }
                float mv = bv[0]; int mp = 0;
#pragma unroll
                for (int t = 1; t < T; ++t)
                    if (bv[t] < mv) { mv = bv[t]; mp = t; }
                curmin = mv; minpos = mp;
            }
        }
        __syncthreads();   // merge reads done before next staging overwrites ks/sc
    }

    // exact top-32 among the group's 192 candidates on the f32 screen scores
    // (f32 order, lower index on ties — jax.lax.top_k semantics)
    unsigned cons = 0;
    float m0 = 0.0f;
    double sum_part = 0.0;
#pragma unroll 1
    for (int t32 = 0; t32 < TK; ++t32) {
        float lm = -INFINITY; int li = 0x7fffffff; int lp = -1;
#pragma unroll
        for (int t = 0; t < T; ++t) {
            bool ok = !(cons & (1u << t));
            if (ok && (bv[t] > lm || (bv[t] == lm && bi[t] < li))) {
                lm = bv[t]; li = bi[t]; lp = t;
            }
        }
        float gv = lm; int gi = li;
#pragma unroll
        for (int k = 1; k < 8; k <<= 1) {
            float ov = __shfl_xor(gv, k);
            int   oi = __shfl_xor(gi, k);
            if (ov > gv || (ov == gv && oi < gi)) { gv = ov; gi = oi; }
        }
        if (lp >= 0 && gv == lm && gi == li) cons |= 1u << lp;   // winner's owner consumes
        if (t32 == 0) m0 = gv;
        if ((t32 & 7) == j) {
            double e = exp((double)(gv - m0));
            sum_part += e;
            isel[r][t32] = gi;
            wsel[r][t32] = (float)e;       // unnormalized; rescaled below
        }
    }
#pragma unroll
    for (int k = 1; k < 8; k <<= 1) sum_part += __shfl_xor(sum_part, k);
    {
        double inv = 1.0 / sum_part;
#pragma unroll
        for (int tt = 0; tt < 4; ++tt) {
            int t = 8 * tt + j;
            wsel[r][t] = (float)((double)wsel[r][t] * inv);
        }
    }
    __syncthreads();

    // PV: gather selected V rows (f32), write X[b, q, h*64+d]
    {
        int rr = tid >> 3, d0 = (tid & 7) * 8;
        float4 a0 = {0, 0, 0, 0}, a1 = {0, 0, 0, 0};
#pragma unroll 1
        for (int t = 0; t < TK; ++t) {
            float ww = wsel[rr][t];
            int mi   = isel[rr][t];
            const float* vp = Vp + ((size_t)(b * LM + mi) * D + h * DK + d0);
            float4 v0 = *(const float4*)vp;
            float4 v1 = *(const float4*)(vp + 4);
            a0.x = fmaf(ww, v0.x, a0.x); a0.y = fmaf(ww, v0.y, a0.y);
            a0.z = fmaf(ww, v0.z, a0.z); a0.w = fmaf(ww, v0.w, a0.w);
            a1.x = fmaf(ww, v1.x, a1.x); a1.y = fmaf(ww, v1.y, a1.y);
            a1.z = fmaf(ww, v1.z, a1.z); a1.w = fmaf(ww, v1.w, a1.w);
        }
        float* xp = Xp + ((size_t)(b * LQ + qt * QT + rr) * D + h * DK + d0);
        *(float4*)xp       = a0;
        *(float4*)(xp + 4) = a1;
    }
}

extern "C" void kernel_launch(void* const* d_in, const int* in_sizes, int n_in,
                              void* d_out, int out_size, void* d_ws, size_t ws_size,
                              hipStream_t stream) {
    const float* query = (const float*)d_in[0];
    const float* key   = (const float*)d_in[1];
    const float* value = (const float*)d_in[2];
    const float* Wq    = (const float*)d_in[3];
    const float* bq    = (const float*)d_in[4];
    const float* Wk    = (const float*)d_in[5];
    const float* bk    = (const float*)d_in[6];
    const float* Wv    = (const float*)d_in[7];
    const float* bv    = (const float*)d_in[8];
    const float* Wo    = (const float*)d_in[9];
    const float* bo    = (const float*)d_in[10];
    float* out = (float*)d_out;

    // ws: V f32 [32768,512] | X f32 [8192,512] | Q f32 [8192,512] | K f32 [32768,512]  (160 MB)
    float* Vp = (float*)d_ws;
    float* Xp = Vp + (size_t)32768 * 512;
    float* Qf = Xp + (size_t)8192 * 512;
    float* Kf = Qf + (size_t)8192 * 512;

    dim3 blk(256);
    gemm_qkv<<<dim3(8, 1152), blk, 0, stream>>>(query, key, value,
                                                Wq, Wk, Wv, bq, bk, bv,
                                                Qf, Kf, Vp);
    topk_attn_fused<<<dim3(32, 8, 8), blk, 0, stream>>>(Qf, Kf, Vp, Xp);
    gemm_nt512<<<dim3(8, 128), blk, 0, stream>>>(Xp, Wo, bo, out);
}